// Round 4
// baseline (40.575 us; speedup 1.0000x reference)
//
#include <hip/hip_runtime.h>

// Shapes (compile-time constants from the reference)
#define BQ 4     // B
#define VV 384   // V visible nodes
#define HH 128   // H hidden nodes
#define NN 512   // N = V + H
#define HDIM 64  // HD
#define TD 128   // T*D

// ws layout (in floats):
#define OFF_E2    0                               // B*N*64 = 131072
#define OFF_WIN1T (BQ * NN * HDIM)                // 64 x 128 (o,k)
#define OFF_WIN2T (OFF_WIN1T + HDIM * TD)         // 64 x 64
#define OFF_WE1ST (OFF_WIN2T + HDIM * HDIM)       // 64 x 64 (sender half of w_e1)
#define OFF_WE2T  (OFF_WE1ST + HDIM * HDIM)       // 64 x 64
#define OFF_WN1T  (OFF_WE2T + HDIM * HDIM)        // 64 x 64
#define OFF_WN2T  (OFF_WN1T + HDIM * HDIM)        // 64 x 64
#define OFF_WOUTT (OFF_WN2T + HDIM * HDIM)        // 128 x 64 (o,k)

// K0: transpose weights from (K,O) to (O,K) so each lane can stream its own
// contiguous row with float4 loads.
__global__ __launch_bounds__(256) void k_prep(
    const float* __restrict__ w_in1, const float* __restrict__ w_in2,
    const float* __restrict__ w_e1,  const float* __restrict__ w_e2,
    const float* __restrict__ w_n1,  const float* __restrict__ w_n2,
    const float* __restrict__ w_out, float* __restrict__ ws)
{
    const int id = blockIdx.x * blockDim.x + threadIdx.x;
    const int stride = gridDim.x * blockDim.x;
    // w_in1 (128,64) -> (64,128)
    for (int t = id; t < HDIM * TD; t += stride) {
        const int o = t / TD, k = t % TD;
        ws[OFF_WIN1T + t] = w_in1[k * HDIM + o];
    }
    // 64x64 transposes
    for (int t = id; t < HDIM * HDIM; t += stride) {
        const int o = t / HDIM, k = t % HDIM;
        ws[OFF_WIN2T + t] = w_in2[k * HDIM + o];
        ws[OFF_WE1ST + t] = w_e1[(HDIM + k) * HDIM + o];
        ws[OFF_WE2T  + t] = w_e2[k * HDIM + o];
        ws[OFF_WN1T  + t] = w_n1[k * HDIM + o];
        ws[OFF_WN2T  + t] = w_n2[k * HDIM + o];
    }
    // w_out (64,128) -> (128,64)
    for (int t = id; t < TD * HDIM; t += stride) {
        const int o = t / HDIM, k = t % HDIM;
        ws[OFF_WOUTT + t] = w_out[k * TD + o];
    }
}

// K1: per-row pipeline. One wave per (b, j) row.
__global__ __launch_bounds__(256) void k_rowpipe(
    const float* __restrict__ x,       // (B,V,128)
    const float* __restrict__ b_in1, const float* __restrict__ b_in2,
    const float* __restrict__ b_e1,  const float* __restrict__ b_e2,
    const float* __restrict__ ws,      // transposed weights
    float* __restrict__ E2)            // (B,N,64)
{
    const int wave = (blockIdx.x * blockDim.x + threadIdx.x) >> 6;
    const int lane = threadIdx.x & 63;
    if (wave >= BQ * NN) return;
    const int b = wave / NN;
    const int j = wave % NN;

    float bbv = 0.f;
    if (j < VV) {  // wave-uniform branch
        const float* xr = x + (size_t)(b * VV + j) * TD;
        const float xv0 = xr[lane];
        const float xv1 = xr[64 + lane];

        // layer in1: K=128. lane's weight row is contiguous 128 floats.
        const float4* w1r = (const float4*)(ws + OFF_WIN1T) + lane * (TD / 4);
        float a0 = b_in1[lane], a1 = 0.f, a2 = 0.f, a3 = 0.f;
        #pragma unroll
        for (int q = 0; q < 16; ++q) {
            const float4 wa = w1r[q];
            a0 = fmaf(__shfl(xv0, 4 * q,     64), wa.x, a0);
            a1 = fmaf(__shfl(xv0, 4 * q + 1, 64), wa.y, a1);
            a2 = fmaf(__shfl(xv0, 4 * q + 2, 64), wa.z, a2);
            a3 = fmaf(__shfl(xv0, 4 * q + 3, 64), wa.w, a3);
            const float4 wb = w1r[16 + q];
            a0 = fmaf(__shfl(xv1, 4 * q,     64), wb.x, a0);
            a1 = fmaf(__shfl(xv1, 4 * q + 1, 64), wb.y, a1);
            a2 = fmaf(__shfl(xv1, 4 * q + 2, 64), wb.z, a2);
            a3 = fmaf(__shfl(xv1, 4 * q + 3, 64), wb.w, a3);
        }
        const float h1 = fmaxf((a0 + a1) + (a2 + a3), 0.f);

        // layer in2: K=64
        const float4* w2r = (const float4*)(ws + OFF_WIN2T) + lane * (HDIM / 4);
        a0 = b_in2[lane]; a1 = 0.f; a2 = 0.f; a3 = 0.f;
        #pragma unroll
        for (int q = 0; q < 16; ++q) {
            const float4 wa = w2r[q];
            a0 = fmaf(__shfl(h1, 4 * q,     64), wa.x, a0);
            a1 = fmaf(__shfl(h1, 4 * q + 1, 64), wa.y, a1);
            a2 = fmaf(__shfl(h1, 4 * q + 2, 64), wa.z, a2);
            a3 = fmaf(__shfl(h1, 4 * q + 3, 64), wa.w, a3);
        }
        const float h2 = fmaxf((a0 + a1) + (a2 + a3), 0.f);

        // sender-side edge contribution
        const float4* wer = (const float4*)(ws + OFF_WE1ST) + lane * (HDIM / 4);
        a0 = 0.f; a1 = 0.f; a2 = 0.f; a3 = 0.f;
        #pragma unroll
        for (int q = 0; q < 16; ++q) {
            const float4 wa = wer[q];
            a0 = fmaf(__shfl(h2, 4 * q,     64), wa.x, a0);
            a1 = fmaf(__shfl(h2, 4 * q + 1, 64), wa.y, a1);
            a2 = fmaf(__shfl(h2, 4 * q + 2, 64), wa.z, a2);
            a3 = fmaf(__shfl(h2, 4 * q + 3, 64), wa.w, a3);
        }
        bbv = (a0 + a1) + (a2 + a3);
    }

    const float e1 = fmaxf(bbv + b_e1[lane], 0.f);
    const float4* w3r = (const float4*)(ws + OFF_WE2T) + lane * (HDIM / 4);
    float a0 = b_e2[lane], a1 = 0.f, a2 = 0.f, a3 = 0.f;
    #pragma unroll
    for (int q = 0; q < 16; ++q) {
        const float4 wa = w3r[q];
        a0 = fmaf(__shfl(e1, 4 * q,     64), wa.x, a0);
        a1 = fmaf(__shfl(e1, 4 * q + 1, 64), wa.y, a1);
        a2 = fmaf(__shfl(e1, 4 * q + 2, 64), wa.z, a2);
        a3 = fmaf(__shfl(e1, 4 * q + 3, 64), wa.w, a3);
    }
    E2[(size_t)wave * HDIM + lane] = fmaxf((a0 + a1) + (a2 + a3), 0.f);
}

// K2: one block (8 waves, 512 threads) per hidden receiver row (b, i=V+hi).
__global__ __launch_bounds__(512) void k_agg_out(
    const float* __restrict__ adj,   // (B,N,N)
    const float* __restrict__ E2,    // (B,N,64)
    const float* __restrict__ b_n1, const float* __restrict__ b_n2,
    const float* __restrict__ b_out, // (128)
    const float* __restrict__ ws,    // transposed weights
    float* __restrict__ out)         // (B,H,128)
{
    const int row  = blockIdx.x;          // 0 .. B*H-1
    const int b    = row / HH;
    const int hi   = row % HH;
    const int i    = VV + hi;
    const int wid  = threadIdx.x >> 6;    // 0..7
    const int lane = threadIdx.x & 63;

    const float* adjrow = adj + ((size_t)b * NN + i) * NN;
    const float* e2b    = E2 + ((size_t)b * NN + wid * 64) * HDIM;

    const float adjv = adjrow[wid * 64 + lane];

    float c0 = 0.f, c1 = 0.f, c2 = 0.f, c3 = 0.f;
    #pragma unroll
    for (int jj = 0; jj < 64; jj += 4) {
        c0 = fmaf(__shfl(adjv, jj,     64), e2b[(jj)     * HDIM + lane], c0);
        c1 = fmaf(__shfl(adjv, jj + 1, 64), e2b[(jj + 1) * HDIM + lane], c1);
        c2 = fmaf(__shfl(adjv, jj + 2, 64), e2b[(jj + 2) * HDIM + lane], c2);
        c3 = fmaf(__shfl(adjv, jj + 3, 64), e2b[(jj + 3) * HDIM + lane], c3);
    }

    __shared__ float red[8][HDIM];
    red[wid][lane] = (c0 + c1) + (c2 + c3);
    __syncthreads();
    if (wid != 0) return;

    const float acc = ((red[0][lane] + red[1][lane]) + (red[2][lane] + red[3][lane]))
                    + ((red[4][lane] + red[5][lane]) + (red[6][lane] + red[7][lane]));

    const float4* wn1r = (const float4*)(ws + OFF_WN1T) + lane * (HDIM / 4);
    float t0 = b_n1[lane], t1 = 0.f, t2 = 0.f, t3 = 0.f;
    #pragma unroll
    for (int q = 0; q < 16; ++q) {
        const float4 wa = wn1r[q];
        t0 = fmaf(__shfl(acc, 4 * q,     64), wa.x, t0);
        t1 = fmaf(__shfl(acc, 4 * q + 1, 64), wa.y, t1);
        t2 = fmaf(__shfl(acc, 4 * q + 2, 64), wa.z, t2);
        t3 = fmaf(__shfl(acc, 4 * q + 3, 64), wa.w, t3);
    }
    const float n1 = fmaxf((t0 + t1) + (t2 + t3), 0.f);

    const float4* wn2r = (const float4*)(ws + OFF_WN2T) + lane * (HDIM / 4);
    t0 = b_n2[lane]; t1 = 0.f; t2 = 0.f; t3 = 0.f;
    #pragma unroll
    for (int q = 0; q < 16; ++q) {
        const float4 wa = wn2r[q];
        t0 = fmaf(__shfl(n1, 4 * q,     64), wa.x, t0);
        t1 = fmaf(__shfl(n1, 4 * q + 1, 64), wa.y, t1);
        t2 = fmaf(__shfl(n1, 4 * q + 2, 64), wa.z, t2);
        t3 = fmaf(__shfl(n1, 4 * q + 3, 64), wa.w, t3);
    }
    const float n2 = fmaxf((t0 + t1) + (t2 + t3), 0.f);

    // out row: lane covers cols lane and 64+lane; rows lane / 64+lane of (128,64)
    const float4* wo0 = (const float4*)(ws + OFF_WOUTT) + lane * (HDIM / 4);
    const float4* wo1 = wo0 + 64 * (HDIM / 4);
    float o0a = b_out[lane],      o0b = 0.f;
    float o1a = b_out[64 + lane], o1b = 0.f;
    #pragma unroll
    for (int q = 0; q < 16; ++q) {
        const float v0 = __shfl(n2, 4 * q,     64);
        const float v1 = __shfl(n2, 4 * q + 1, 64);
        const float v2 = __shfl(n2, 4 * q + 2, 64);
        const float v3 = __shfl(n2, 4 * q + 3, 64);
        const float4 wa = wo0[q];
        o0a = fmaf(v0, wa.x, o0a);
        o0b = fmaf(v1, wa.y, o0b);
        o0a = fmaf(v2, wa.z, o0a);
        o0b = fmaf(v3, wa.w, o0b);
        const float4 wb = wo1[q];
        o1a = fmaf(v0, wb.x, o1a);
        o1b = fmaf(v1, wb.y, o1b);
        o1a = fmaf(v2, wb.z, o1a);
        o1b = fmaf(v3, wb.w, o1b);
    }
    float* orow = out + (size_t)row * TD;
    orow[lane]      = o0a + o0b;
    orow[64 + lane] = o1a + o1b;
}

extern "C" void kernel_launch(void* const* d_in, const int* in_sizes, int n_in,
                              void* d_out, int out_size, void* d_ws, size_t ws_size,
                              hipStream_t stream) {
    const float* x     = (const float*)d_in[0];
    const float* adj   = (const float*)d_in[1];
    const float* w_in1 = (const float*)d_in[2];
    const float* b_in1 = (const float*)d_in[3];
    const float* w_in2 = (const float*)d_in[4];
    const float* b_in2 = (const float*)d_in[5];
    const float* w_e1  = (const float*)d_in[6];
    const float* b_e1  = (const float*)d_in[7];
    const float* w_e2  = (const float*)d_in[8];
    const float* b_e2  = (const float*)d_in[9];
    const float* w_n1  = (const float*)d_in[10];
    const float* b_n1  = (const float*)d_in[11];
    const float* w_n2  = (const float*)d_in[12];
    const float* b_n2  = (const float*)d_in[13];
    const float* w_out = (const float*)d_in[14];
    const float* b_out = (const float*)d_in[15];
    float* out = (float*)d_out;
    float* ws  = (float*)d_ws;
    float* E2  = ws + OFF_E2;

    k_prep<<<128, 256, 0, stream>>>(w_in1, w_in2, w_e1, w_e2, w_n1, w_n2, w_out, ws);
    k_rowpipe<<<(BQ * NN * 64) / 256, 256, 0, stream>>>(
        x, b_in1, b_in2, b_e1, b_e2, ws, E2);
    k_agg_out<<<BQ * HH, 512, 0, stream>>>(
        adj, E2, b_n1, b_n2, b_out, ws, out);
}